// Round 6
// baseline (6518.027 us; speedup 1.0000x reference)
//
#include <hip/hip_runtime.h>
#include <cstddef>

#define TSTEPS 365
#define NGRID_ 2000
#define NX_ 16
#define H_ 256
#define CPB 32
#define NBLK ((NGRID_ + CPB - 1) / CPB)   // 63 blocks, 1024 threads each

typedef __attribute__((ext_vector_type(8))) short short8v;
typedef __attribute__((ext_vector_type(4))) float f32x4;

__device__ __forceinline__ unsigned short f2bf(float f) {
    unsigned int u = __float_as_uint(f);
    u += 0x7fffu + ((u >> 16) & 1u);   // round-to-nearest-even
    return (unsigned short)(u >> 16);
}
__device__ __forceinline__ float bf2f(unsigned short s) {
    return __uint_as_float(((unsigned int)s) << 16);
}
__device__ __forceinline__ float sigmoid_f(float v) {
    return 1.0f / (1.0f + __expf(-v));
}
__device__ __forceinline__ float tanh_f(float v) {
    return 1.0f - 2.0f / (__expf(2.0f * v) + 1.0f);
}

// ---------------------------------------------------------------------------
// Pack wh [4][256][256] and wx [4][16][256] (fp32) into bf16 MFMA B-fragment
// order (layout validated in rounds 2-5).
// ---------------------------------------------------------------------------
#define WH_WORDS (64 * 8 * 64)
#define WX_WORDS (64 * 64)

__global__ __launch_bounds__(256) void pack_weights(
    const float* __restrict__ wh, const float* __restrict__ wx,
    unsigned short* __restrict__ pb)
{
    int tid = blockIdx.x * 256 + threadIdx.x;
    short8v sv;
    if (tid < WH_WORDS) {
        int lane = tid & 63;
        int kt   = (tid >> 6) & 7;
        int gu   = tid >> 9;
        int g    = gu >> 4;
        int ncol = ((gu & 15) << 4) | (lane & 15);
        int kb   = kt * 32 + ((lane >> 4) << 3);
#pragma unroll
        for (int j = 0; j < 8; ++j)
            sv[j] = (short)f2bf(wh[((size_t)(g * H_ + kb + j)) * H_ + ncol]);
        *(short8v*)(pb + (size_t)tid * 8) = sv;
    } else if (tid < WH_WORDS + WX_WORDS) {
        int t2   = tid - WH_WORDS;
        int lane = t2 & 63;
        int gu   = t2 >> 6;
        int g    = gu >> 4;
        int ncol = ((gu & 15) << 4) | (lane & 15);
        int kkb  = (lane >> 4) << 3;
#pragma unroll
        for (int j = 0; j < 8; ++j) {
            int k = (kkb + j) & 15;
            sv[j] = (short)f2bf(wx[((size_t)(g * NX_ + k)) * H_ + ncol]);
        }
        *(short8v*)(pb + (size_t)tid * 8) = sv;
    }
}

// ---------------------------------------------------------------------------
// Persistent LSTM. Block = 32 cells (2 cell-tiles), 16 waves of 64.
// Wave w owns hidden units [w*16, w*16+16) for all 4 gates.
// KEY FIX vs r5: LDS padded to 84 KB so only ONE block fits per CU ->
// compiler must plan 16 waves/CU = 4 waves/EU -> 128-reg budget per wave
// (r5's 72 KB LDS let it plan 2 blocks/CU -> 64-reg cap -> spill loop).
// Demand ~95 arch + 32 acc < 128 -> zero spill.
// x(t+1) load is async-split (issue at step top, LDS-write after GATES) so
// cold-HBM latency hides under the MFMA phase.
// ---------------------------------------------------------------------------
__attribute__((amdgpu_flat_work_group_size(1024, 1024)))
__attribute__((amdgpu_waves_per_eu(4)))
__global__ void lstm_mfma(
    const float* __restrict__ x,     // [T][NGRID][NX]
    const float* __restrict__ b,     // [4][H]
    const float* __restrict__ wlin,  // [H]
    const float* __restrict__ blin,  // [1]
    const unsigned short* __restrict__ pb,
    float* __restrict__ out)         // [T][NGRID]
{
    __shared__ __align__(16) unsigned short Ah[2][2][32][16][8];  // 32 KB
    __shared__ __align__(16) unsigned short Al[2][2][32][16][8];  // 32 KB
    __shared__ __align__(16) unsigned short Ax[2][2][4][16][8];   // 4 KB
    __shared__ float red[2][16][2][16];                           // 4 KB
    __shared__ float lds_pad[3072];                               // 12 KB pad

    const int tid = threadIdx.x;
    const int w   = tid >> 6;     // wave 0..15
    const int l   = tid & 63;
    const int lg  = l >> 4;
    const int ln  = l & 15;
    const int c0  = blockIdx.x * CPB;

    // keep the pad allocated (branch can't be proven dead at compile time)
    if (blockIdx.x == 0x7fffffff) lds_pad[tid & 1023] = 1.0f;

    float bias[4];
#pragma unroll
    for (int g = 0; g < 4; ++g) bias[g] = b[g * H_ + w * 16 + ln];
    const float wl = wlin[w * 16 + ln];
    const float bl = blin[0];

    const unsigned short* BX = pb + (size_t)WH_WORDS * 8;

    // zero h(-1) buffers (buf 0, both cell-tiles)
    {
        uint4 z = make_uint4(0, 0, 0, 0);
        ((uint4*)&Ah[0][0][0][0][0])[tid] = z;
        ((uint4*)&Al[0][0][0][0][0])[tid] = z;
    }
    // stage x(0): 512 threads = 32 cells x 16 features
    if (tid < 512) {
        const int cell = tid >> 4, nx = tid & 15;
        const int gc = c0 + cell;
        float v = (gc < NGRID_) ? x[(size_t)gc * NX_ + nx] : 0.0f;
        unsigned short hi = f2bf(v);
        unsigned short lo = f2bf(v - bf2f(hi));
        Ax[0][cell >> 4][nx >> 3][cell & 15][nx & 7] = hi;
        Ax[0][cell >> 4][2 + (nx >> 3)][cell & 15][nx & 7] = lo;
    }

    // preload kt=0 wh chunks (gu = g*16 + w)
    short8v bbA[4], bbB[4];
#pragma unroll
    for (int g = 0; g < 4; ++g) {
        int gu = (g << 4) | w;
        bbA[g] = *(const short8v*)(pb + (((size_t)gu * 8 + 0) * 64 + l) * 8);
    }

    __syncthreads();

    f32x4 acc0[4], acc1[4];   // [gate], cell-tile 0 / 1
    float cst[2][4];          // [ct][r]
#pragma unroll
    for (int ct = 0; ct < 2; ++ct)
#pragma unroll
        for (int r = 0; r < 4; ++r) cst[ct][r] = 0.0f;

#define KT_ROUND(KT, CUR, NXT, LOADKT)                                         \
    {                                                                          \
        _Pragma("unroll")                                                      \
        for (int g = 0; g < 4; ++g) {                                          \
            int gu = (g << 4) | w;                                             \
            NXT[g] = *(const short8v*)(pb + (((size_t)gu * 8 + (LOADKT)) * 64 + l) * 8); \
        }                                                                      \
        short8v ah0 = *(const short8v*)&Ah[rb][0][(KT) * 4 + lg][ln][0];       \
        short8v al0 = *(const short8v*)&Al[rb][0][(KT) * 4 + lg][ln][0];       \
        short8v ah1 = *(const short8v*)&Ah[rb][1][(KT) * 4 + lg][ln][0];       \
        short8v al1 = *(const short8v*)&Al[rb][1][(KT) * 4 + lg][ln][0];       \
        _Pragma("unroll")                                                      \
        for (int g = 0; g < 4; ++g) {                                          \
            acc0[g] = __builtin_amdgcn_mfma_f32_16x16x32_bf16(ah0, CUR[g], acc0[g], 0, 0, 0); \
            acc0[g] = __builtin_amdgcn_mfma_f32_16x16x32_bf16(al0, CUR[g], acc0[g], 0, 0, 0); \
            acc1[g] = __builtin_amdgcn_mfma_f32_16x16x32_bf16(ah1, CUR[g], acc1[g], 0, 0, 0); \
            acc1[g] = __builtin_amdgcn_mfma_f32_16x16x32_bf16(al1, CUR[g], acc1[g], 0, 0, 0); \
        }                                                                      \
    }

#pragma unroll 1
    for (int t = 0; t < TSTEPS; ++t) {
        const int rb = t & 1, wb = rb ^ 1;

        // T14 async split: issue x(t+1) load NOW, consume after GATES.
        float xv = 0.0f;
        const bool xload = (t + 1 < TSTEPS) && (tid < 512);
        const int xcell = tid >> 4, xnx = tid & 15;
        if (xload) {
            const int gc = c0 + xcell;
            xv = (gc < NGRID_)
                     ? x[(((size_t)(t + 1)) * NGRID_ + gc) * NX_ + xnx]
                     : 0.0f;
        }

#pragma unroll
        for (int g = 0; g < 4; ++g) {
            f32x4 a0 = {bias[g], bias[g], bias[g], bias[g]};
            acc0[g] = a0;
            acc1[g] = a0;
        }

        KT_ROUND(0, bbA, bbB, 1)
        KT_ROUND(1, bbB, bbA, 2)
        KT_ROUND(2, bbA, bbB, 3)
        KT_ROUND(3, bbB, bbA, 4)
        KT_ROUND(4, bbA, bbB, 5)
        KT_ROUND(5, bbB, bbA, 6)
        KT_ROUND(6, bbA, bbB, 7)
        KT_ROUND(7, bbB, bbA, 0)   // prefetch next step's kt=0 into bbA

        // x projection round: bx is transient (bbB dead here)
        {
            short8v bx[4];
#pragma unroll
            for (int g = 0; g < 4; ++g) {
                int gu = (g << 4) | w;
                bx[g] = *(const short8v*)(BX + ((size_t)gu * 64 + l) * 8);
            }
            short8v ax0 = *(const short8v*)&Ax[rb][0][lg][ln][0];
            short8v ax1 = *(const short8v*)&Ax[rb][1][lg][ln][0];
#pragma unroll
            for (int g = 0; g < 4; ++g) {
                acc0[g] = __builtin_amdgcn_mfma_f32_16x16x32_bf16(ax0, bx[g], acc0[g], 0, 0, 0);
                acc1[g] = __builtin_amdgcn_mfma_f32_16x16x32_bf16(ax1, bx[g], acc1[g], 0, 0, 0);
            }
        }

        // gates + state + publish h + output partials, per cell-tile
#define GATES(ACC, CT)                                                         \
        {                                                                      \
            float hN[4];                                                       \
            _Pragma("unroll")                                                  \
            for (int r = 0; r < 4; ++r) {                                      \
                float ig = sigmoid_f(ACC[0][r]);                               \
                float fg = sigmoid_f(ACC[1][r]);                               \
                float gt = tanh_f(ACC[2][r]);                                  \
                float og = sigmoid_f(ACC[3][r]);                               \
                float c  = fmaf(fg, cst[CT][r], ig * gt);                      \
                cst[CT][r] = c;                                                \
                hN[r] = og * tanh_f(c);                                        \
            }                                                                  \
            {                                                                  \
                int u = w * 16 + ln;                                           \
                _Pragma("unroll")                                              \
                for (int r = 0; r < 4; ++r) {                                  \
                    int cell = lg * 4 + r;                                     \
                    unsigned short hi = f2bf(hN[r]);                           \
                    Ah[wb][CT][u >> 3][cell][u & 7] = hi;                      \
                    Al[wb][CT][u >> 3][cell][u & 7] = f2bf(hN[r] - bf2f(hi));  \
                }                                                              \
            }                                                                  \
            float p[4];                                                        \
            _Pragma("unroll")                                                  \
            for (int r = 0; r < 4; ++r) {                                      \
                p[r] = hN[r] * wl;                                             \
                _Pragma("unroll")                                              \
                for (int off = 1; off < 16; off <<= 1)                         \
                    p[r] += __shfl_xor(p[r], off);                             \
            }                                                                  \
            if (ln == 0) {                                                     \
                _Pragma("unroll")                                              \
                for (int r = 0; r < 4; ++r) red[rb][w][CT][lg * 4 + r] = p[r]; \
            }                                                                  \
        }

        GATES(acc0, 0)
        GATES(acc1, 1)

        // complete the async x staging (load has had the whole step to land)
        if (xload) {
            unsigned short hi = f2bf(xv);
            unsigned short lo = f2bf(xv - bf2f(hi));
            Ax[wb][xcell >> 4][xnx >> 3][xcell & 15][xnx & 7] = hi;
            Ax[wb][xcell >> 4][2 + (xnx >> 3)][xcell & 15][xnx & 7] = lo;
        }

        __syncthreads();

        if (tid < CPB) {
            const int gc = c0 + tid;
            if (gc < NGRID_) {
                float s = bl;
#pragma unroll
                for (int w2 = 0; w2 < 16; ++w2)
                    s += red[rb][w2][tid >> 4][tid & 15];
                out[(size_t)t * NGRID_ + gc] = s;
            }
        }
    }
#undef KT_ROUND
#undef GATES
}

extern "C" void kernel_launch(void* const* d_in, const int* in_sizes, int n_in,
                              void* d_out, int out_size, void* d_ws, size_t ws_size,
                              hipStream_t stream) {
    const float* x    = (const float*)d_in[0];
    const float* wx   = (const float*)d_in[1];
    const float* wh   = (const float*)d_in[2];
    const float* b    = (const float*)d_in[3];
    const float* wlin = (const float*)d_in[4];
    const float* blin = (const float*)d_in[5];
    float* out = (float*)d_out;
    unsigned short* pb = (unsigned short*)d_ws;   // 576 KB

    hipLaunchKernelGGL(pack_weights, dim3((WH_WORDS + WX_WORDS) / 256), dim3(256),
                       0, stream, wh, wx, pb);
    hipLaunchKernelGGL(lstm_mfma, dim3(NBLK), dim3(1024), 0, stream,
                       x, b, wlin, blin, pb, out);
}

// Round 7
// 6517.725 us; speedup vs baseline: 1.0000x; 1.0000x over previous
//
#include <hip/hip_runtime.h>
#include <cstddef>

#define TSTEPS 365
#define NGRID_ 2000
#define NX_ 16
#define H_ 256
#define CPB 32
#define NBLK ((NGRID_ + CPB - 1) / CPB)   // 63 blocks, 1024 threads each

typedef __attribute__((ext_vector_type(8))) short short8v;
typedef __attribute__((ext_vector_type(4))) float f32x4;

__device__ __forceinline__ unsigned short f2bf(float f) {
    unsigned int u = __float_as_uint(f);
    u += 0x7fffu + ((u >> 16) & 1u);   // round-to-nearest-even
    return (unsigned short)(u >> 16);
}
__device__ __forceinline__ float bf2f(unsigned short s) {
    return __uint_as_float(((unsigned int)s) << 16);
}
__device__ __forceinline__ float sigmoid_f(float v) {
    return 1.0f / (1.0f + __expf(-v));
}
__device__ __forceinline__ float tanh_f(float v) {
    return 1.0f - 2.0f / (__expf(2.0f * v) + 1.0f);
}

// ---------------------------------------------------------------------------
// Pack wh [4][256][256] and wx [4][16][256] (fp32) into bf16 MFMA B-fragment
// order (layout validated in rounds 2-6).
// ---------------------------------------------------------------------------
#define WH_WORDS (64 * 8 * 64)
#define WX_WORDS (64 * 64)

__global__ __launch_bounds__(256) void pack_weights(
    const float* __restrict__ wh, const float* __restrict__ wx,
    unsigned short* __restrict__ pb)
{
    int tid = blockIdx.x * 256 + threadIdx.x;
    short8v sv;
    if (tid < WH_WORDS) {
        int lane = tid & 63;
        int kt   = (tid >> 6) & 7;
        int gu   = tid >> 9;
        int g    = gu >> 4;
        int ncol = ((gu & 15) << 4) | (lane & 15);
        int kb   = kt * 32 + ((lane >> 4) << 3);
#pragma unroll
        for (int j = 0; j < 8; ++j)
            sv[j] = (short)f2bf(wh[((size_t)(g * H_ + kb + j)) * H_ + ncol]);
        *(short8v*)(pb + (size_t)tid * 8) = sv;
    } else if (tid < WH_WORDS + WX_WORDS) {
        int t2   = tid - WH_WORDS;
        int lane = t2 & 63;
        int gu   = t2 >> 6;
        int g    = gu >> 4;
        int ncol = ((gu & 15) << 4) | (lane & 15);
        int kkb  = (lane >> 4) << 3;
#pragma unroll
        for (int j = 0; j < 8; ++j) {
            int k = (kkb + j) & 15;
            sv[j] = (short)f2bf(wx[((size_t)(g * NX_ + k)) * H_ + ncol]);
        }
        *(short8v*)(pb + (size_t)tid * 8) = sv;
    }
}

// ---------------------------------------------------------------------------
// Persistent LSTM. Block = 32 cells (2 cell-tiles), 16 waves of 64.
// Wave w owns hidden units [w*16, w*16+16) for all 4 gates.
//
// Occupancy clamp (r6 post-mortem): we NEED 1 block/CU = 4 waves/EU so the
// allocator budgets 128 VGPRs/wave (demand ~104). Two redundant mechanisms:
//   (a) LDS padded to 88 KB with a GENUINELY live pad array (read+written
//       under a runtime-data branch that escapes to out) -> 2 blocks can't
//       fit -> 1 block/CU is the only compile-time-legal occupancy.
//   (b) amdgpu_waves_per_eu(4,4): min=max=4 waves/EU -> 128-reg budget.
// r3-r6 all spilled because the compiler planned 2 blocks/CU (64/128-reg
// caps vs 104-190 demand): WRITE_SIZE 31 MB over output, FETCH 140 MB over
// input = scratch traffic.
// ---------------------------------------------------------------------------
__attribute__((amdgpu_flat_work_group_size(1024, 1024)))
__attribute__((amdgpu_waves_per_eu(4, 4)))
__global__ void lstm_mfma(
    const float* __restrict__ x,     // [T][NGRID][NX]
    const float* __restrict__ b,     // [4][H]
    const float* __restrict__ wlin,  // [H]
    const float* __restrict__ blin,  // [1]
    const unsigned short* __restrict__ pb,
    float* __restrict__ out)         // [T][NGRID]
{
    __shared__ __align__(16) unsigned short Ah[2][2][32][16][8];  // 32 KB
    __shared__ __align__(16) unsigned short Al[2][2][32][16][8];  // 32 KB
    __shared__ __align__(16) unsigned short Ax[2][2][4][16][8];   // 4 KB
    __shared__ float red[2][16][2][16];                           // 4 KB
    __shared__ float lds_pad[4096];                               // 16 KB pad

    const int tid = threadIdx.x;
    const int w   = tid >> 6;     // wave 0..15
    const int l   = tid & 63;
    const int lg  = l >> 4;
    const int ln  = l & 15;
    const int c0  = blockIdx.x * CPB;

    float bias[4];
#pragma unroll
    for (int g = 0; g < 4; ++g) bias[g] = b[g * H_ + w * 16 + ln];
    const float wl = wlin[w * 16 + ln];
    const float bl = blin[0];

    // Live LDS pad: blin[0] is runtime data (~0.06 magnitude), so this branch
    // never executes, but the compiler cannot prove it -> the write AND the
    // escaping read keep all 16 KB allocated. Forces LDS=88 KB -> 1 block/CU.
    if (__builtin_expect(bl > 1e30f, 0)) {
        lds_pad[tid] = bl;
        lds_pad[tid + 1024] = bl * 2.0f;
        lds_pad[tid + 2048] = bl * 3.0f;
        lds_pad[tid + 3072] = bl * 4.0f;
        __syncthreads();
        out[0] = lds_pad[(tid * 37) & 4095];
    }

    const unsigned short* BX = pb + (size_t)WH_WORDS * 8;

    // zero h(-1) buffers (buf 0, both cell-tiles)
    {
        uint4 z = make_uint4(0, 0, 0, 0);
        ((uint4*)&Ah[0][0][0][0][0])[tid] = z;
        ((uint4*)&Al[0][0][0][0][0])[tid] = z;
    }
    // stage x(0): 512 threads = 32 cells x 16 features
    if (tid < 512) {
        const int cell = tid >> 4, nx = tid & 15;
        const int gc = c0 + cell;
        float v = (gc < NGRID_) ? x[(size_t)gc * NX_ + nx] : 0.0f;
        unsigned short hi = f2bf(v);
        unsigned short lo = f2bf(v - bf2f(hi));
        Ax[0][cell >> 4][nx >> 3][cell & 15][nx & 7] = hi;
        Ax[0][cell >> 4][2 + (nx >> 3)][cell & 15][nx & 7] = lo;
    }

    // preload kt=0 wh chunks (gu = g*16 + w)
    short8v bbA[4], bbB[4];
#pragma unroll
    for (int g = 0; g < 4; ++g) {
        int gu = (g << 4) | w;
        bbA[g] = *(const short8v*)(pb + (((size_t)gu * 8 + 0) * 64 + l) * 8);
    }

    __syncthreads();

    f32x4 acc0[4], acc1[4];   // [gate], cell-tile 0 / 1
    float cst[2][4];          // [ct][r]
#pragma unroll
    for (int ct = 0; ct < 2; ++ct)
#pragma unroll
        for (int r = 0; r < 4; ++r) cst[ct][r] = 0.0f;

#define KT_ROUND(KT, CUR, NXT, LOADKT)                                         \
    {                                                                          \
        _Pragma("unroll")                                                      \
        for (int g = 0; g < 4; ++g) {                                          \
            int gu = (g << 4) | w;                                             \
            NXT[g] = *(const short8v*)(pb + (((size_t)gu * 8 + (LOADKT)) * 64 + l) * 8); \
        }                                                                      \
        short8v ah0 = *(const short8v*)&Ah[rb][0][(KT) * 4 + lg][ln][0];       \
        short8v al0 = *(const short8v*)&Al[rb][0][(KT) * 4 + lg][ln][0];       \
        short8v ah1 = *(const short8v*)&Ah[rb][1][(KT) * 4 + lg][ln][0];       \
        short8v al1 = *(const short8v*)&Al[rb][1][(KT) * 4 + lg][ln][0];       \
        _Pragma("unroll")                                                      \
        for (int g = 0; g < 4; ++g) {                                          \
            acc0[g] = __builtin_amdgcn_mfma_f32_16x16x32_bf16(ah0, CUR[g], acc0[g], 0, 0, 0); \
            acc0[g] = __builtin_amdgcn_mfma_f32_16x16x32_bf16(al0, CUR[g], acc0[g], 0, 0, 0); \
            acc1[g] = __builtin_amdgcn_mfma_f32_16x16x32_bf16(ah1, CUR[g], acc1[g], 0, 0, 0); \
            acc1[g] = __builtin_amdgcn_mfma_f32_16x16x32_bf16(al1, CUR[g], acc1[g], 0, 0, 0); \
        }                                                                      \
    }

#pragma unroll 1
    for (int t = 0; t < TSTEPS; ++t) {
        const int rb = t & 1, wb = rb ^ 1;

        // T14 async split: issue x(t+1) load NOW, consume after GATES.
        float xv = 0.0f;
        const bool xload = (t + 1 < TSTEPS) && (tid < 512);
        const int xcell = tid >> 4, xnx = tid & 15;
        if (xload) {
            const int gc = c0 + xcell;
            xv = (gc < NGRID_)
                     ? x[(((size_t)(t + 1)) * NGRID_ + gc) * NX_ + xnx]
                     : 0.0f;
        }

#pragma unroll
        for (int g = 0; g < 4; ++g) {
            f32x4 a0 = {bias[g], bias[g], bias[g], bias[g]};
            acc0[g] = a0;
            acc1[g] = a0;
        }

        KT_ROUND(0, bbA, bbB, 1)
        KT_ROUND(1, bbB, bbA, 2)
        KT_ROUND(2, bbA, bbB, 3)
        KT_ROUND(3, bbB, bbA, 4)
        KT_ROUND(4, bbA, bbB, 5)
        KT_ROUND(5, bbB, bbA, 6)
        KT_ROUND(6, bbA, bbB, 7)
        KT_ROUND(7, bbB, bbA, 0)   // prefetch next step's kt=0 into bbA

        // x projection round: bx is transient (bbB dead here)
        {
            short8v bx[4];
#pragma unroll
            for (int g = 0; g < 4; ++g) {
                int gu = (g << 4) | w;
                bx[g] = *(const short8v*)(BX + ((size_t)gu * 64 + l) * 8);
            }
            short8v ax0 = *(const short8v*)&Ax[rb][0][lg][ln][0];
            short8v ax1 = *(const short8v*)&Ax[rb][1][lg][ln][0];
#pragma unroll
            for (int g = 0; g < 4; ++g) {
                acc0[g] = __builtin_amdgcn_mfma_f32_16x16x32_bf16(ax0, bx[g], acc0[g], 0, 0, 0);
                acc1[g] = __builtin_amdgcn_mfma_f32_16x16x32_bf16(ax1, bx[g], acc1[g], 0, 0, 0);
            }
        }

        // gates + state + publish h + output partials, per cell-tile
#define GATES(ACC, CT)                                                         \
        {                                                                      \
            float hN[4];                                                       \
            _Pragma("unroll")                                                  \
            for (int r = 0; r < 4; ++r) {                                      \
                float ig = sigmoid_f(ACC[0][r]);                               \
                float fg = sigmoid_f(ACC[1][r]);                               \
                float gt = tanh_f(ACC[2][r]);                                  \
                float og = sigmoid_f(ACC[3][r]);                               \
                float c  = fmaf(fg, cst[CT][r], ig * gt);                      \
                cst[CT][r] = c;                                                \
                hN[r] = og * tanh_f(c);                                        \
            }                                                                  \
            {                                                                  \
                int u = w * 16 + ln;                                           \
                _Pragma("unroll")                                              \
                for (int r = 0; r < 4; ++r) {                                  \
                    int cell = lg * 4 + r;                                     \
                    unsigned short hi = f2bf(hN[r]);                           \
                    Ah[wb][CT][u >> 3][cell][u & 7] = hi;                      \
                    Al[wb][CT][u >> 3][cell][u & 7] = f2bf(hN[r] - bf2f(hi));  \
                }                                                              \
            }                                                                  \
            float p[4];                                                        \
            _Pragma("unroll")                                                  \
            for (int r = 0; r < 4; ++r) {                                      \
                p[r] = hN[r] * wl;                                             \
                _Pragma("unroll")                                              \
                for (int off = 1; off < 16; off <<= 1)                         \
                    p[r] += __shfl_xor(p[r], off);                             \
            }                                                                  \
            if (ln == 0) {                                                     \
                _Pragma("unroll")                                              \
                for (int r = 0; r < 4; ++r) red[rb][w][CT][lg * 4 + r] = p[r]; \
            }                                                                  \
        }

        GATES(acc0, 0)
        GATES(acc1, 1)

        // complete the async x staging (load has had the whole step to land)
        if (xload) {
            unsigned short hi = f2bf(xv);
            unsigned short lo = f2bf(xv - bf2f(hi));
            Ax[wb][xcell >> 4][xnx >> 3][xcell & 15][xnx & 7] = hi;
            Ax[wb][xcell >> 4][2 + (xnx >> 3)][xcell & 15][xnx & 7] = lo;
        }

        __syncthreads();

        if (tid < CPB) {
            const int gc = c0 + tid;
            if (gc < NGRID_) {
                float s = bl;
#pragma unroll
                for (int w2 = 0; w2 < 16; ++w2)
                    s += red[rb][w2][tid >> 4][tid & 15];
                out[(size_t)t * NGRID_ + gc] = s;
            }
        }
    }
#undef KT_ROUND
#undef GATES
}

extern "C" void kernel_launch(void* const* d_in, const int* in_sizes, int n_in,
                              void* d_out, int out_size, void* d_ws, size_t ws_size,
                              hipStream_t stream) {
    const float* x    = (const float*)d_in[0];
    const float* wx   = (const float*)d_in[1];
    const float* wh   = (const float*)d_in[2];
    const float* b    = (const float*)d_in[3];
    const float* wlin = (const float*)d_in[4];
    const float* blin = (const float*)d_in[5];
    float* out = (float*)d_out;
    unsigned short* pb = (unsigned short*)d_ws;   // 576 KB

    hipLaunchKernelGGL(pack_weights, dim3((WH_WORDS + WX_WORDS) / 256), dim3(256),
                       0, stream, wh, wx, pb);
    hipLaunchKernelGGL(lstm_mfma, dim3(NBLK), dim3(1024), 0, stream,
                       x, b, wlin, blin, pb, out);
}

// Round 8
// 6335.434 us; speedup vs baseline: 1.0288x; 1.0288x over previous
//
#include <hip/hip_runtime.h>
#include <cstddef>

#define TSTEPS 365
#define NGRID_ 2000
#define NX_ 16
#define H_ 256
#define CPB 32
#define NBLK ((NGRID_ + CPB - 1) / CPB)   // 63 blocks, 512 threads each

typedef __attribute__((ext_vector_type(8))) short short8v;
typedef __attribute__((ext_vector_type(4))) float f32x4;

__device__ __forceinline__ unsigned short f2bf(float f) {
    unsigned int u = __float_as_uint(f);
    u += 0x7fffu + ((u >> 16) & 1u);   // round-to-nearest-even
    return (unsigned short)(u >> 16);
}
__device__ __forceinline__ float bf2f(unsigned short s) {
    return __uint_as_float(((unsigned int)s) << 16);
}
__device__ __forceinline__ float sigmoid_f(float v) {
    return 1.0f / (1.0f + __expf(-v));
}
__device__ __forceinline__ float tanh_f(float v) {
    return 1.0f - 2.0f / (__expf(2.0f * v) + 1.0f);
}

// ---------------------------------------------------------------------------
// Pack wh [4][256][256] and wx [4][16][256] (fp32) into bf16 MFMA B-fragment
// order (layout validated in rounds 2-7).
// ---------------------------------------------------------------------------
#define WH_WORDS (64 * 8 * 64)
#define WX_WORDS (64 * 64)

__global__ __launch_bounds__(256) void pack_weights(
    const float* __restrict__ wh, const float* __restrict__ wx,
    unsigned short* __restrict__ pb)
{
    int tid = blockIdx.x * 256 + threadIdx.x;
    short8v sv;
    if (tid < WH_WORDS) {
        int lane = tid & 63;
        int kt   = (tid >> 6) & 7;
        int gu   = tid >> 9;
        int g    = gu >> 4;
        int ncol = ((gu & 15) << 4) | (lane & 15);
        int kb   = kt * 32 + ((lane >> 4) << 3);
#pragma unroll
        for (int j = 0; j < 8; ++j)
            sv[j] = (short)f2bf(wh[((size_t)(g * H_ + kb + j)) * H_ + ncol]);
        *(short8v*)(pb + (size_t)tid * 8) = sv;
    } else if (tid < WH_WORDS + WX_WORDS) {
        int t2   = tid - WH_WORDS;
        int lane = t2 & 63;
        int gu   = t2 >> 6;
        int g    = gu >> 4;
        int ncol = ((gu & 15) << 4) | (lane & 15);
        int kkb  = (lane >> 4) << 3;
#pragma unroll
        for (int j = 0; j < 8; ++j) {
            int k = (kkb + j) & 15;
            sv[j] = (short)f2bf(wx[((size_t)(g * NX_ + k)) * H_ + ncol]);
        }
        *(short8v*)(pb + (size_t)tid * 8) = sv;
    }
}

// ---------------------------------------------------------------------------
// Persistent LSTM. Block = 32 cells, 512 threads (8 waves).
// Wave w owns units [w*32, w*32+32) (unit-subgroups j=0,1) x 4 gates, for
// BOTH cell-tiles: acc[g][j][ct] = 16 f32x4 = 64 VGPRs.
//
// Register-budget rule (empirical, r1-r7): allocator budget = 65536/threads,
// regardless of LDS size, launch_bounds 2nd arg, or amdgpu_waves_per_eu.
// 512 threads -> 128-reg budget. This kernel's demand ~126:
//   acc 64 + cst 16 + A-frag 16 + B transient 8 + bias 8 + misc ~14.
// B chunks are loaded per-gate (transient) -- NOT pinned/double-buffered
// (r3 pinned 96 regs of B and spilled). Latency hiding comes from TLP
// (~4 waves/SIMD), not per-wave ILP.
// ---------------------------------------------------------------------------
__global__ __launch_bounds__(512) void lstm_mfma(
    const float* __restrict__ x,     // [T][NGRID][NX]
    const float* __restrict__ b,     // [4][H]
    const float* __restrict__ wlin,  // [H]
    const float* __restrict__ blin,  // [1]
    const unsigned short* __restrict__ pb,
    float* __restrict__ out)         // [T][NGRID]
{
    __shared__ __align__(16) unsigned short Ah[2][32][32][8];  // 32 KB
    __shared__ __align__(16) unsigned short Al[2][32][32][8];  // 32 KB
    __shared__ __align__(16) unsigned short Ax[2][4][32][8];   // 4 KB
    __shared__ float red[2][8][32];                            // 2 KB

    const int tid = threadIdx.x;
    const int w   = tid >> 6;     // wave 0..7
    const int l   = tid & 63;
    const int lg  = l >> 4;
    const int ln  = l & 15;
    const int c0  = blockIdx.x * CPB;

    float bias[4][2];
#pragma unroll
    for (int g = 0; g < 4; ++g)
#pragma unroll
        for (int j = 0; j < 2; ++j)
            bias[g][j] = b[g * H_ + w * 32 + j * 16 + ln];
    float wl[2];
    wl[0] = wlin[w * 32 + ln];
    wl[1] = wlin[w * 32 + 16 + ln];
    const float bl = blin[0];

    const unsigned short* BX = pb + (size_t)WH_WORDS * 8;

    // zero h(-1) buffer 0: 16 KB each array = 1024 uint4
    {
        uint4 z = make_uint4(0, 0, 0, 0);
        ((uint4*)&Ah[0][0][0][0])[tid]       = z;
        ((uint4*)&Ah[0][0][0][0])[tid + 512] = z;
        ((uint4*)&Al[0][0][0][0])[tid]       = z;
        ((uint4*)&Al[0][0][0][0])[tid + 512] = z;
    }
    // stage x(0): 512 threads = 32 cells x 16 features
    {
        const int cell = tid >> 4, nx = tid & 15;
        const int gc = c0 + cell;
        float v = (gc < NGRID_) ? x[(size_t)gc * NX_ + nx] : 0.0f;
        unsigned short hi = f2bf(v);
        unsigned short lo = f2bf(v - bf2f(hi));
        Ax[0][nx >> 3][cell][nx & 7]     = hi;
        Ax[0][2 + (nx >> 3)][cell][nx & 7] = lo;
    }
    __syncthreads();

    f32x4 acc[4][2][2];   // [gate][unit-subgroup j][cell-tile ct]
    float cst[2][2][4];   // [j][ct][r]
#pragma unroll
    for (int j = 0; j < 2; ++j)
#pragma unroll
        for (int ct = 0; ct < 2; ++ct)
#pragma unroll
            for (int r = 0; r < 4; ++r) cst[j][ct][r] = 0.0f;

#define KT_ROUND(KT)                                                           \
    {                                                                          \
        short8v ah0 = *(const short8v*)&Ah[rb][(KT) * 4 + lg][ln][0];          \
        short8v al0 = *(const short8v*)&Al[rb][(KT) * 4 + lg][ln][0];          \
        short8v ah1 = *(const short8v*)&Ah[rb][(KT) * 4 + lg][16 + ln][0];     \
        short8v al1 = *(const short8v*)&Al[rb][(KT) * 4 + lg][16 + ln][0];     \
        _Pragma("unroll")                                                      \
        for (int g = 0; g < 4; ++g) {                                          \
            short8v b0 = *(const short8v*)(pb +                                \
                (((size_t)((g << 4) | (w * 2 + 0)) * 8 + (KT)) * 64 + l) * 8); \
            short8v b1 = *(const short8v*)(pb +                                \
                (((size_t)((g << 4) | (w * 2 + 1)) * 8 + (KT)) * 64 + l) * 8); \
            acc[g][0][0] = __builtin_amdgcn_mfma_f32_16x16x32_bf16(ah0, b0, acc[g][0][0], 0, 0, 0); \
            acc[g][0][0] = __builtin_amdgcn_mfma_f32_16x16x32_bf16(al0, b0, acc[g][0][0], 0, 0, 0); \
            acc[g][0][1] = __builtin_amdgcn_mfma_f32_16x16x32_bf16(ah1, b0, acc[g][0][1], 0, 0, 0); \
            acc[g][0][1] = __builtin_amdgcn_mfma_f32_16x16x32_bf16(al1, b0, acc[g][0][1], 0, 0, 0); \
            acc[g][1][0] = __builtin_amdgcn_mfma_f32_16x16x32_bf16(ah0, b1, acc[g][1][0], 0, 0, 0); \
            acc[g][1][0] = __builtin_amdgcn_mfma_f32_16x16x32_bf16(al0, b1, acc[g][1][0], 0, 0, 0); \
            acc[g][1][1] = __builtin_amdgcn_mfma_f32_16x16x32_bf16(ah1, b1, acc[g][1][1], 0, 0, 0); \
            acc[g][1][1] = __builtin_amdgcn_mfma_f32_16x16x32_bf16(al1, b1, acc[g][1][1], 0, 0, 0); \
        }                                                                      \
    }

#pragma unroll 1
    for (int t = 0; t < TSTEPS; ++t) {
        const int rb = t & 1, wb = rb ^ 1;

#pragma unroll
        for (int g = 0; g < 4; ++g)
#pragma unroll
            for (int j = 0; j < 2; ++j) {
                f32x4 a0 = {bias[g][j], bias[g][j], bias[g][j], bias[g][j]};
                acc[g][j][0] = a0;
                acc[g][j][1] = a0;
            }

        KT_ROUND(0) KT_ROUND(1) KT_ROUND(2) KT_ROUND(3)
        KT_ROUND(4) KT_ROUND(5) KT_ROUND(6) KT_ROUND(7)

        // x projection round (x hi in k0..15, lo in k16..31; B = [wx;wx])
        {
            short8v ax0 = *(const short8v*)&Ax[rb][lg][ln][0];
            short8v ax1 = *(const short8v*)&Ax[rb][lg][16 + ln][0];
#pragma unroll
            for (int g = 0; g < 4; ++g) {
                short8v bx0 = *(const short8v*)(BX +
                    ((size_t)((g << 4) | (w * 2 + 0)) * 64 + l) * 8);
                short8v bx1 = *(const short8v*)(BX +
                    ((size_t)((g << 4) | (w * 2 + 1)) * 64 + l) * 8);
                acc[g][0][0] = __builtin_amdgcn_mfma_f32_16x16x32_bf16(ax0, bx0, acc[g][0][0], 0, 0, 0);
                acc[g][0][1] = __builtin_amdgcn_mfma_f32_16x16x32_bf16(ax1, bx0, acc[g][0][1], 0, 0, 0);
                acc[g][1][0] = __builtin_amdgcn_mfma_f32_16x16x32_bf16(ax0, bx1, acc[g][1][0], 0, 0, 0);
                acc[g][1][1] = __builtin_amdgcn_mfma_f32_16x16x32_bf16(ax1, bx1, acc[g][1][1], 0, 0, 0);
            }
        }

        // gates + state + publish h(t) + output partials
        float p[2][4];
#pragma unroll
        for (int ct = 0; ct < 2; ++ct)
#pragma unroll
            for (int r = 0; r < 4; ++r) p[ct][r] = 0.0f;

#pragma unroll
        for (int j = 0; j < 2; ++j) {
            const int u = w * 32 + j * 16 + ln;
#pragma unroll
            for (int ct = 0; ct < 2; ++ct)
#pragma unroll
                for (int r = 0; r < 4; ++r) {
                    float ig = sigmoid_f(acc[0][j][ct][r]);
                    float fg = sigmoid_f(acc[1][j][ct][r]);
                    float gt = tanh_f(acc[2][j][ct][r]);
                    float og = sigmoid_f(acc[3][j][ct][r]);
                    float c  = fmaf(fg, cst[j][ct][r], ig * gt);
                    cst[j][ct][r] = c;
                    float h = og * tanh_f(c);
                    const int cell = ct * 16 + lg * 4 + r;
                    unsigned short hi = f2bf(h);
                    Ah[wb][u >> 3][cell][u & 7] = hi;
                    Al[wb][u >> 3][cell][u & 7] = f2bf(h - bf2f(hi));
                    p[ct][r] = fmaf(h, wl[j], p[ct][r]);
                }
        }
        // reduce p over the 16 lanes of each lane-group
#pragma unroll
        for (int ct = 0; ct < 2; ++ct)
#pragma unroll
            for (int r = 0; r < 4; ++r) {
#pragma unroll
                for (int off = 1; off < 16; off <<= 1)
                    p[ct][r] += __shfl_xor(p[ct][r], off);
                if (ln == 0) red[rb][w][ct * 16 + lg * 4 + r] = p[ct][r];
            }

        // stage x(t+1)
        if (t + 1 < TSTEPS) {
            const int cell = tid >> 4, nx = tid & 15;
            const int gc = c0 + cell;
            float v = (gc < NGRID_)
                          ? x[(((size_t)(t + 1)) * NGRID_ + gc) * NX_ + nx]
                          : 0.0f;
            unsigned short hi = f2bf(v);
            unsigned short lo = f2bf(v - bf2f(hi));
            Ax[wb][nx >> 3][cell][nx & 7]       = hi;
            Ax[wb][2 + (nx >> 3)][cell][nx & 7] = lo;
        }

        __syncthreads();   // h(t), x(t+1), red visible; all rb reads complete

        if (tid < CPB) {
            const int gc = c0 + tid;
            if (gc < NGRID_) {
                float s = bl;
#pragma unroll
                for (int w2 = 0; w2 < 8; ++w2) s += red[rb][w2][tid];
                out[(size_t)t * NGRID_ + gc] = s;
            }
        }
    }
#undef KT_ROUND
}

extern "C" void kernel_launch(void* const* d_in, const int* in_sizes, int n_in,
                              void* d_out, int out_size, void* d_ws, size_t ws_size,
                              hipStream_t stream) {
    const float* x    = (const float*)d_in[0];
    const float* wx   = (const float*)d_in[1];
    const float* wh   = (const float*)d_in[2];
    const float* b    = (const float*)d_in[3];
    const float* wlin = (const float*)d_in[4];
    const float* blin = (const float*)d_in[5];
    float* out = (float*)d_out;
    unsigned short* pb = (unsigned short*)d_ws;   // 576 KB

    hipLaunchKernelGGL(pack_weights, dim3((WH_WORDS + WX_WORDS) / 256), dim3(256),
                       0, stream, wh, wx, pb);
    hipLaunchKernelGGL(lstm_mfma, dim3(NBLK), dim3(512), 0, stream,
                       x, b, wlin, blin, pb, out);
}